// Round 1
// baseline (1461.545 us; speedup 1.0000x reference)
//
#include <hip/hip_runtime.h>
#include <math.h>

#define B_ 4
#define C_ 128
#define N_ 4096
#define CG 16          // channels per group (128/8)
#define QT 32          // query tile
#define MT 64          // key/value tile

// ---------------- GroupNorm: one block per (b, group) ----------------
__global__ __launch_bounds__(256) void gn_kernel(
    const float* __restrict__ x, const float* __restrict__ scale,
    const float* __restrict__ bias, float* __restrict__ h) {
  int b = blockIdx.x >> 3, g = blockIdx.x & 7;
  const float4* xp = (const float4*)(x + (size_t)(b * C_ + g * CG) * N_);
  float4* hp = (float4*)(h + (size_t)(b * C_ + g * CG) * N_);
  const int NV = CG * N_ / 4;  // 16384 float4 per group
  float s = 0.f, ss = 0.f;
  for (int i = threadIdx.x; i < NV; i += 256) {
    float4 v = xp[i];
    s += v.x + v.y + v.z + v.w;
    ss += v.x * v.x + v.y * v.y + v.z * v.z + v.w * v.w;
  }
  #pragma unroll
  for (int o = 32; o > 0; o >>= 1) {
    s += __shfl_down(s, o, 64);
    ss += __shfl_down(ss, o, 64);
  }
  __shared__ float rs[4], rss[4];
  __shared__ float smu, srstd;
  int wid = threadIdx.x >> 6, lane = threadIdx.x & 63;
  if (lane == 0) { rs[wid] = s; rss[wid] = ss; }
  __syncthreads();
  if (threadIdx.x == 0) {
    float S = rs[0] + rs[1] + rs[2] + rs[3];
    float SS = rss[0] + rss[1] + rss[2] + rss[3];
    float mu = S / (float)(CG * N_);
    float var = SS / (float)(CG * N_) - mu * mu;
    smu = mu;
    srstd = rsqrtf(var + 1e-6f);
  }
  __syncthreads();
  float mu = smu, rstd = srstd;
  for (int i = threadIdx.x; i < NV; i += 256) {
    int c = g * CG + (i >> 10);            // (i*4) >> 12
    float sc = scale[c] * rstd;
    float bi = bias[c] - mu * sc;
    float4 v = xp[i];
    v.x = v.x * sc + bi; v.y = v.y * sc + bi;
    v.z = v.z * sc + bi; v.w = v.w * sc + bi;
    hp[i] = v;
  }
}

// ---------------- fused Q/K/V 1x1 conv: block = (b, 32-col tile) ----------------
__global__ __launch_bounds__(256) void qkv_kernel(
    const float* __restrict__ h,
    const float* __restrict__ wq, const float* __restrict__ bq,
    const float* __restrict__ wk, const float* __restrict__ bk,
    const float* __restrict__ wv, const float* __restrict__ bv,
    float* __restrict__ q, float* __restrict__ k, float* __restrict__ v) {
  __shared__ float hs[C_][32];
  int b = blockIdx.x >> 7;
  int n0 = (blockIdx.x & 127) * 32;
  const float* hp = h + (size_t)b * C_ * N_ + n0;
  for (int i = threadIdx.x; i < C_ * 32; i += 256)
    hs[i >> 5][i & 31] = hp[(size_t)(i >> 5) * N_ + (i & 31)];
  __syncthreads();
  int n = threadIdx.x & 31;
  int ob = (threadIdx.x >> 5) * 16;
  size_t base = (size_t)b * C_ * N_ + n0 + n;
  for (int oi = 0; oi < 16; ++oi) {
    int o = ob + oi;
    float aq = bq[o], ak = bk[o], av = bv[o];
    const float4* wq4 = (const float4*)(wq + (size_t)o * C_);
    const float4* wk4 = (const float4*)(wk + (size_t)o * C_);
    const float4* wv4 = (const float4*)(wv + (size_t)o * C_);
    #pragma unroll 4
    for (int c4 = 0; c4 < C_ / 4; ++c4) {
      float4 a = wq4[c4], bb = wk4[c4], cc = wv4[c4];
      int c = c4 * 4;
      float h0 = hs[c][n], h1 = hs[c + 1][n], h2 = hs[c + 2][n], h3 = hs[c + 3][n];
      aq += a.x * h0 + a.y * h1 + a.z * h2 + a.w * h3;
      ak += bb.x * h0 + bb.y * h1 + bb.z * h2 + bb.w * h3;
      av += cc.x * h0 + cc.y * h1 + cc.z * h2 + cc.w * h3;
    }
    q[base + (size_t)o * N_] = aq;
    k[base + (size_t)o * N_] = ak;
    v[base + (size_t)o * N_] = av;
  }
}

// ---------------- flash attention (fp32): block = (b, 32-query tile) ----------------
__global__ __launch_bounds__(256) void attn_kernel(
    const float* __restrict__ q, const float* __restrict__ k,
    const float* __restrict__ v, float* __restrict__ ho) {
  __shared__ float Qs[C_][QT];        // 16 KB
  __shared__ float KVs[C_][MT];       // 32 KB (K, then V)
  __shared__ float Ss[QT][MT + 1];    // ~8.1 KB, padded
  __shared__ float mrow[QT], lrow[QT], arow[QT];
  int b = blockIdx.x >> 7;
  int n0 = (blockIdx.x & 127) * QT;
  const float* qp = q + (size_t)b * C_ * N_ + n0;
  const float* kp = k + (size_t)b * C_ * N_;
  const float* vp = v + (size_t)b * C_ * N_;
  for (int i = threadIdx.x; i < C_ * QT; i += 256)
    Qs[i >> 5][i & 31] = qp[(size_t)(i >> 5) * N_ + (i & 31)];
  if (threadIdx.x < QT) { mrow[threadIdx.x] = -1e30f; lrow[threadIdx.x] = 0.f; }
  int n = threadIdx.x & 31;
  int grp = threadIdx.x >> 5;  // 0..7
  float Oacc[16];
  #pragma unroll
  for (int i = 0; i < 16; ++i) Oacc[i] = 0.f;
  const float scl = 0.08838834764831845f;  // 128^-0.5
  for (int m0 = 0; m0 < N_; m0 += MT) {
    __syncthreads();   // previous PV done before K overwrite
    for (int i = threadIdx.x; i < C_ * MT; i += 256)
      KVs[i >> 6][i & 63] = kp[(size_t)(i >> 6) * N_ + m0 + (i & 63)];
    __syncthreads();
    {  // S[n][grp*8 .. +8) = scale * q_n . k_m
      float acc[8];
      #pragma unroll
      for (int j = 0; j < 8; ++j) acc[j] = 0.f;
      int mb = grp * 8;
      for (int c = 0; c < C_; ++c) {
        float qv = Qs[c][n];
        const float4* kr = (const float4*)(&KVs[c][mb]);
        float4 k0 = kr[0], k1 = kr[1];
        acc[0] += qv * k0.x; acc[1] += qv * k0.y;
        acc[2] += qv * k0.z; acc[3] += qv * k0.w;
        acc[4] += qv * k1.x; acc[5] += qv * k1.y;
        acc[6] += qv * k1.z; acc[7] += qv * k1.w;
      }
      #pragma unroll
      for (int j = 0; j < 8; ++j) Ss[n][mb + j] = acc[j] * scl;
    }
    __syncthreads();
    if (threadIdx.x < QT) {  // online softmax, one thread per row
      int r = threadIdx.x;
      float mold = mrow[r];
      float mx = mold;
      #pragma unroll 8
      for (int m = 0; m < MT; ++m) mx = fmaxf(mx, Ss[r][m]);
      float alpha = expf(mold - mx);
      float lsum = 0.f;
      #pragma unroll 8
      for (int m = 0; m < MT; ++m) {
        float p = expf(Ss[r][m] - mx);
        Ss[r][m] = p;
        lsum += p;
      }
      mrow[r] = mx;
      lrow[r] = lrow[r] * alpha + lsum;
      arow[r] = alpha;
    }
    __syncthreads();
    float alpha = arow[n];
    #pragma unroll
    for (int i = 0; i < 16; ++i) Oacc[i] *= alpha;
    for (int i = threadIdx.x; i < C_ * MT; i += 256)   // V over K in LDS
      KVs[i >> 6][i & 63] = vp[(size_t)(i >> 6) * N_ + m0 + (i & 63)];
    __syncthreads();
    for (int m = 0; m < MT; ++m) {
      float p = Ss[n][m];
      #pragma unroll
      for (int i = 0; i < 16; ++i)
        Oacc[i] += p * KVs[grp * 16 + i][m];
    }
  }
  float linv = 1.0f / lrow[n];
  float* hop = ho + (size_t)b * C_ * N_ + n0 + n;
  #pragma unroll
  for (int i = 0; i < 16; ++i)
    hop[(size_t)(grp * 16 + i) * N_] = Oacc[i] * linv;
}

// ---------------- proj 1x1 conv + residual ----------------
__global__ __launch_bounds__(256) void proj_kernel(
    const float* __restrict__ hh, const float* __restrict__ wp,
    const float* __restrict__ bp, const float* __restrict__ x,
    float* __restrict__ out) {
  __shared__ float hs[C_][32];
  int b = blockIdx.x >> 7;
  int n0 = (blockIdx.x & 127) * 32;
  const float* hp = hh + (size_t)b * C_ * N_ + n0;
  for (int i = threadIdx.x; i < C_ * 32; i += 256)
    hs[i >> 5][i & 31] = hp[(size_t)(i >> 5) * N_ + (i & 31)];
  __syncthreads();
  int n = threadIdx.x & 31;
  int ob = (threadIdx.x >> 5) * 16;
  size_t base = (size_t)b * C_ * N_ + n0 + n;
  for (int oi = 0; oi < 16; ++oi) {
    int o = ob + oi;
    float acc = bp[o];
    const float4* w4 = (const float4*)(wp + (size_t)o * C_);
    #pragma unroll 4
    for (int c4 = 0; c4 < C_ / 4; ++c4) {
      float4 a = w4[c4];
      int c = c4 * 4;
      acc += a.x * hs[c][n] + a.y * hs[c + 1][n] +
             a.z * hs[c + 2][n] + a.w * hs[c + 3][n];
    }
    out[base + (size_t)o * N_] = acc + x[base + (size_t)o * N_];
  }
}

extern "C" void kernel_launch(void* const* d_in, const int* in_sizes, int n_in,
                              void* d_out, int out_size, void* d_ws, size_t ws_size,
                              hipStream_t stream) {
  const float* x        = (const float*)d_in[0];
  const float* gn_scale = (const float*)d_in[1];
  const float* gn_bias  = (const float*)d_in[2];
  const float* wq = (const float*)d_in[3];
  const float* bq = (const float*)d_in[4];
  const float* wk = (const float*)d_in[5];
  const float* bk = (const float*)d_in[6];
  const float* wv = (const float*)d_in[7];
  const float* bv = (const float*)d_in[8];
  const float* wp = (const float*)d_in[9];
  const float* bp = (const float*)d_in[10];
  float* out = (float*)d_out;

  // workspace: h (reused as h_), q, k, v — each B*C*N = 2,097,152 floats
  const size_t SZ = (size_t)B_ * C_ * N_;
  float* h  = (float*)d_ws;
  float* qb = h + SZ;
  float* kb = qb + SZ;
  float* vb = kb + SZ;

  gn_kernel<<<32, 256, 0, stream>>>(x, gn_scale, gn_bias, h);
  qkv_kernel<<<512, 256, 0, stream>>>(h, wq, bq, wk, bk, wv, bv, qb, kb, vb);
  attn_kernel<<<512, 256, 0, stream>>>(qb, kb, vb, h);   // h_ overwrites h
  proj_kernel<<<512, 256, 0, stream>>>(h, wp, bp, x, out);
}

// Round 3
// 409.875 us; speedup vs baseline: 3.5658x; 3.5658x over previous
//
#include <hip/hip_runtime.h>
#include <math.h>

#define B_ 4
#define C_ 128
#define N_ 4096
#define CG 16           // channels per group (128/8)
#define NSPLIT 4        // KV splits (flash-decode style)
#define MT 32           // KV tile per iteration
#define KLD 136         // Ks row stride (bf16 elems): 128 + 8 pad, 16B-aligned
#define VLD 40          // Vs/Ps row stride: 32 + 8 pad, 16B-aligned

typedef float floatx4 __attribute__((ext_vector_type(4)));
typedef short short8 __attribute__((ext_vector_type(8)));

__device__ __forceinline__ ushort f2bf(float f) {  // RNE float->bf16 bits
  unsigned u = __float_as_uint(f);
  return (ushort)((u + 0x7FFF + ((u >> 16) & 1)) >> 16);
}
__device__ __forceinline__ float bf2f(ushort u) {
  return __uint_as_float(((unsigned)u) << 16);
}
// 16-lane (DPP row) reductions: result replicated to all 16 lanes of each row.
// ctrl must be a compile-time constant -> template parameter.
template <int CTRL>
__device__ __forceinline__ float dpp_mov(float x) {
  return __int_as_float(__builtin_amdgcn_update_dpp(0, __float_as_int(x), CTRL, 0xF, 0xF, true));
}
__device__ __forceinline__ float red16_max(float x) {
  x = fmaxf(x, dpp_mov<0xB1>(x));   // quad_perm [1,0,3,2]  (xor 1)
  x = fmaxf(x, dpp_mov<0x4E>(x));   // quad_perm [2,3,0,1]  (xor 2)
  x = fmaxf(x, dpp_mov<0x141>(x));  // row_half_mirror      (crosses 4-groups)
  x = fmaxf(x, dpp_mov<0x140>(x));  // row_mirror           (crosses 8-groups)
  return x;
}
__device__ __forceinline__ float red16_sum(float x) {
  x += dpp_mov<0xB1>(x);
  x += dpp_mov<0x4E>(x);
  x += dpp_mov<0x141>(x);
  x += dpp_mov<0x140>(x);
  return x;
}

// ---------------- GroupNorm -> bf16 h: one block per (b, group) ----------------
__global__ __launch_bounds__(256) void gn_kernel(
    const float* __restrict__ x, const float* __restrict__ scale,
    const float* __restrict__ bias, ushort* __restrict__ h) {
  int b = blockIdx.x >> 3, g = blockIdx.x & 7;
  const float4* xp = (const float4*)(x + (size_t)(b * C_ + g * CG) * N_);
  ushort* hp = h + (size_t)(b * C_ + g * CG) * N_;
  const int NV = CG * N_ / 4;
  float s = 0.f, ss = 0.f;
  for (int i = threadIdx.x; i < NV; i += 256) {
    float4 v = xp[i];
    s += v.x + v.y + v.z + v.w;
    ss += v.x * v.x + v.y * v.y + v.z * v.z + v.w * v.w;
  }
  #pragma unroll
  for (int o = 32; o > 0; o >>= 1) {
    s += __shfl_down(s, o, 64);
    ss += __shfl_down(ss, o, 64);
  }
  __shared__ float rs[4], rss[4], smu, srstd;
  int wid = threadIdx.x >> 6, lane = threadIdx.x & 63;
  if (lane == 0) { rs[wid] = s; rss[wid] = ss; }
  __syncthreads();
  if (threadIdx.x == 0) {
    float S = rs[0] + rs[1] + rs[2] + rs[3];
    float SS = rss[0] + rss[1] + rss[2] + rss[3];
    float mu = S / (float)(CG * N_);
    float var = SS / (float)(CG * N_) - mu * mu;
    smu = mu; srstd = rsqrtf(var + 1e-6f);
  }
  __syncthreads();
  float mu = smu, rstd = srstd;
  for (int i = threadIdx.x; i < NV; i += 256) {
    int c = g * CG + (i >> 10);
    float sc = scale[c] * rstd;
    float bi = bias[c] - mu * sc;
    float4 v = xp[i];
    uint2 o2;
    o2.x = (unsigned)f2bf(v.x * sc + bi) | ((unsigned)f2bf(v.y * sc + bi) << 16);
    o2.y = (unsigned)f2bf(v.z * sc + bi) | ((unsigned)f2bf(v.w * sc + bi) << 16);
    ((uint2*)hp)[i] = o2;
  }
}

// ---------- QKV 1x1 conv (fp32 math), writes qT/kT (B,N,C) bf16 (q pre-scaled), v (B,C,N) bf16 ----------
__global__ __launch_bounds__(256) void qkv_kernel(
    const ushort* __restrict__ h,
    const float* __restrict__ wq, const float* __restrict__ bq,
    const float* __restrict__ wk, const float* __restrict__ bk,
    const float* __restrict__ wv, const float* __restrict__ bv,
    ushort* __restrict__ qT, ushort* __restrict__ kT, ushort* __restrict__ vB) {
  __shared__ float hs[C_][32];
  int b = blockIdx.x >> 7;
  int n0 = (blockIdx.x & 127) * 32;
  const ushort* hp = h + (size_t)b * C_ * N_ + n0;
  for (int i = threadIdx.x; i < C_ * 4; i += 256) {   // 512 uint4 = 128 rows x 32 bf16
    int c = i >> 2, u4 = i & 3;
    uint4 d = ((const uint4*)(hp + (size_t)c * N_))[u4];
    unsigned w0[4] = {d.x, d.y, d.z, d.w};
    #pragma unroll
    for (int j = 0; j < 4; ++j) {
      hs[c][u4 * 8 + j * 2]     = __uint_as_float(w0[j] << 16);
      hs[c][u4 * 8 + j * 2 + 1] = __uint_as_float(w0[j] & 0xFFFF0000u);
    }
  }
  __syncthreads();
  int n = threadIdx.x & 31;
  int ob = (threadIdx.x >> 5) * 16;
  const float scl = 0.08838834764831845f;  // 128^-0.5 folded into q
  union U16 { ushort u[16]; uint4 v[2]; } qu, ku;
  for (int oi = 0; oi < 16; ++oi) {
    int o = ob + oi;
    float aq = bq[o], ak = bk[o], av = bv[o];
    const float4* wq4 = (const float4*)(wq + (size_t)o * C_);
    const float4* wk4 = (const float4*)(wk + (size_t)o * C_);
    const float4* wv4 = (const float4*)(wv + (size_t)o * C_);
    #pragma unroll 4
    for (int c4 = 0; c4 < C_ / 4; ++c4) {
      float4 a = wq4[c4], bb = wk4[c4], cc = wv4[c4];
      int c = c4 * 4;
      float h0 = hs[c][n], h1 = hs[c + 1][n], h2 = hs[c + 2][n], h3 = hs[c + 3][n];
      aq += a.x * h0 + a.y * h1 + a.z * h2 + a.w * h3;
      ak += bb.x * h0 + bb.y * h1 + bb.z * h2 + bb.w * h3;
      av += cc.x * h0 + cc.y * h1 + cc.z * h2 + cc.w * h3;
    }
    qu.u[oi] = f2bf(aq * scl);
    ku.u[oi] = f2bf(ak);
    vB[((size_t)b * C_ + o) * N_ + n0 + n] = f2bf(av);
  }
  size_t toff = ((size_t)b * N_ + n0 + n) * C_ + ob;
  ((uint4*)(qT + toff))[0] = qu.v[0]; ((uint4*)(qT + toff))[1] = qu.v[1];
  ((uint4*)(kT + toff))[0] = ku.v[0]; ((uint4*)(kT + toff))[1] = ku.v[1];
}

// ---------------- MFMA flash attention, KV split 4 ways ----------------
// grid 512: sp = bx&3, qblk = (bx>>2)&31, b = bx>>7.  block = 128 thr (2 waves, 64 q-rows each)
__global__ __launch_bounds__(128, 1) void attn_kernel(
    const ushort* __restrict__ qT, const ushort* __restrict__ kT,
    const ushort* __restrict__ vB, ushort* __restrict__ Op,
    float* __restrict__ Mv, float* __restrict__ Lv) {
  __shared__ __align__(16) ushort Ks[MT * KLD];      // 8704 B
  __shared__ __align__(16) ushort Vs[C_ * VLD];      // 10240 B
  __shared__ __align__(16) ushort QPs[128 * 128];    // 32 KB: Q staging, then P (128 x VLD)
  int sp = blockIdx.x & 3;
  int qblk = (blockIdx.x >> 2) & 31;
  int b = blockIdx.x >> 7;
  int n0 = qblk * 128;
  int tid = threadIdx.x;
  int lane = tid & 63, w = tid >> 6;
  int col = lane & 15, quad = lane >> 4;

  const ushort* qTb = qT + ((size_t)b * N_ + n0) * C_;
  const ushort* kTb = kT + (size_t)b * N_ * C_;
  const ushort* vBb = vB + (size_t)b * C_ * N_;

  // stage Q tile (128 q x 128 c) into QPs
  for (int i = tid; i < 2048; i += 128) {
    int row = i >> 4, c8 = i & 15;
    uint4 d = ((const uint4*)(qTb + (size_t)row * C_))[c8];
    *(uint4*)&QPs[row * 128 + c8 * 8] = d;
  }
  __syncthreads();
  // per-wave register-resident Q fragments: 4 qtiles x 4 kc
  short8 qf[4][4];
  #pragma unroll
  for (int qt = 0; qt < 4; ++qt)
    #pragma unroll
    for (int kc = 0; kc < 4; ++kc)
      qf[qt][kc] = *(const short8*)&QPs[(w * 64 + qt * 16 + col) * 128 + kc * 32 + quad * 8];

  floatx4 Oacc[4][8];
  #pragma unroll
  for (int qt = 0; qt < 4; ++qt)
    #pragma unroll
    for (int ct = 0; ct < 8; ++ct) Oacc[qt][ct] = (floatx4)0.f;
  float mrun[4][4], lrun[4][4];
  #pragma unroll
  for (int qt = 0; qt < 4; ++qt)
    #pragma unroll
    for (int r = 0; r < 4; ++r) { mrun[qt][r] = -1e30f; lrun[qt][r] = 0.f; }

  for (int it = 0; it < 1024 / MT; ++it) {
    int m0 = sp * 1024 + it * MT;
    __syncthreads();   // protect Ks/Vs/Ps from previous iteration's readers
    for (int i = tid; i < 512; i += 128) {           // K tile: 32 rows x 128 c
      int row = i >> 4, c8 = i & 15;
      uint4 d = ((const uint4*)(kTb + (size_t)(m0 + row) * C_))[c8];
      *(uint4*)&Ks[row * KLD + c8 * 8] = d;
    }
    for (int i = tid; i < 512; i += 128) {           // V tile: 128 c x 32 m
      int c = i >> 2, m8 = i & 3;
      uint4 d = ((const uint4*)(vBb + (size_t)c * N_ + m0))[m8];
      *(uint4*)&Vs[c * VLD + m8 * 8] = d;
    }
    __syncthreads();

    // K fragments once, reused across 4 q-tiles
    short8 kf[2][4];
    #pragma unroll
    for (int mt = 0; mt < 2; ++mt)
      #pragma unroll
      for (int kc = 0; kc < 4; ++kc)
        kf[mt][kc] = *(const short8*)&Ks[(mt * 16 + col) * KLD + kc * 32 + quad * 8];

    #pragma unroll
    for (int qt = 0; qt < 4; ++qt) {
      floatx4 s0 = (floatx4)0.f, s1 = (floatx4)0.f;
      #pragma unroll
      for (int kc = 0; kc < 4; ++kc) {
        s0 = __builtin_amdgcn_mfma_f32_16x16x32_bf16(qf[qt][kc], kf[0][kc], s0, 0, 0, 0);
        s1 = __builtin_amdgcn_mfma_f32_16x16x32_bf16(qf[qt][kc], kf[1][kc], s1, 0, 0, 0);
      }
      // online softmax: lane holds rows q = qt*16 + quad*4 + r, cols m = {col, 16+col}
      #pragma unroll
      for (int r = 0; r < 4; ++r) {
        float a = s0[r], bb = s1[r];
        float mx = red16_max(fmaxf(a, bb));
        float mnew = fmaxf(mrun[qt][r], mx);
        float al = __expf(mrun[qt][r] - mnew);
        mrun[qt][r] = mnew;
        float p0 = __expf(a - mnew), p1 = __expf(bb - mnew);
        float rsum = red16_sum(p0 + p1);
        lrun[qt][r] = lrun[qt][r] * al + rsum;
        #pragma unroll
        for (int ct = 0; ct < 8; ++ct) Oacc[qt][ct][r] *= al;
        int prow = w * 64 + qt * 16 + quad * 4 + r;
        QPs[prow * VLD + col]      = f2bf(p0);
        QPs[prow * VLD + 16 + col] = f2bf(p1);
      }
    }
    // PV: A = P fragments (per qtile), B = V fragments (per ctile), K = 32 keys
    short8 pf[4];
    #pragma unroll
    for (int qt = 0; qt < 4; ++qt)
      pf[qt] = *(const short8*)&QPs[(w * 64 + qt * 16 + col) * VLD + quad * 8];
    #pragma unroll
    for (int ct = 0; ct < 8; ++ct) {
      short8 vf = *(const short8*)&Vs[(ct * 16 + col) * VLD + quad * 8];
      #pragma unroll
      for (int qt = 0; qt < 4; ++qt)
        Oacc[qt][ct] = __builtin_amdgcn_mfma_f32_16x16x32_bf16(pf[qt], vf, Oacc[qt][ct], 0, 0, 0);
    }
  }

  // epilogue: unnormalized O' (bf16) + per-row m,l
  ushort* OpB = Op + (((size_t)sp * B_ + b) * C_) * N_;
  #pragma unroll
  for (int qt = 0; qt < 4; ++qt) {
    #pragma unroll
    for (int ct = 0; ct < 8; ++ct) {
      int c = ct * 16 + col;
      #pragma unroll
      for (int r = 0; r < 4; ++r) {
        int n = n0 + w * 64 + qt * 16 + quad * 4 + r;
        OpB[(size_t)c * N_ + n] = f2bf(Oacc[qt][ct][r]);
      }
    }
    if (col == 0) {
      #pragma unroll
      for (int r = 0; r < 4; ++r) {
        int n = n0 + w * 64 + qt * 16 + quad * 4 + r;
        Mv[(size_t)sp * (B_ * N_) + b * N_ + n] = mrun[qt][r];
        Lv[(size_t)sp * (B_ * N_) + b * N_ + n] = lrun[qt][r];
      }
    }
  }
}

// ---------------- merge 4 KV-split partials -> h_ (B,C,N) fp32 ----------------
__global__ __launch_bounds__(256) void merge_kernel(
    const ushort* __restrict__ Op, const float* __restrict__ Mv,
    const float* __restrict__ Lv, float* __restrict__ hO) {
  size_t t = (size_t)blockIdx.x * 256 + threadIdx.x;   // one float4 of n per thread
  size_t e = t * 4;
  int b = (int)(e >> 19);
  int rem = (int)(e & 524287);
  int c = rem >> 12, n = rem & 4095;
  float m[NSPLIT][4], l[NSPLIT][4], o[NSPLIT][4];
  #pragma unroll
  for (int sp = 0; sp < NSPLIT; ++sp) {
    const float4 mm = *(const float4*)&Mv[(size_t)sp * (B_ * N_) + b * N_ + n];
    const float4 ll = *(const float4*)&Lv[(size_t)sp * (B_ * N_) + b * N_ + n];
    m[sp][0] = mm.x; m[sp][1] = mm.y; m[sp][2] = mm.z; m[sp][3] = mm.w;
    l[sp][0] = ll.x; l[sp][1] = ll.y; l[sp][2] = ll.z; l[sp][3] = ll.w;
    uint2 ov = *(const uint2*)&Op[((((size_t)sp * B_ + b) * C_) + c) * N_ + n];
    o[sp][0] = bf2f((ushort)(ov.x & 0xFFFF)); o[sp][1] = bf2f((ushort)(ov.x >> 16));
    o[sp][2] = bf2f((ushort)(ov.y & 0xFFFF)); o[sp][3] = bf2f((ushort)(ov.y >> 16));
  }
  float4 res;
  float* rp = (float*)&res;
  #pragma unroll
  for (int j = 0; j < 4; ++j) {
    float M = m[0][j];
    #pragma unroll
    for (int sp = 1; sp < NSPLIT; ++sp) M = fmaxf(M, m[sp][j]);
    float num = 0.f, den = 0.f;
    #pragma unroll
    for (int sp = 0; sp < NSPLIT; ++sp) {
      float wgt = __expf(m[sp][j] - M);
      num += wgt * o[sp][j];
      den += wgt * l[sp][j];
    }
    rp[j] = num / den;
  }
  *(float4*)&hO[((size_t)b * C_ + c) * N_ + n] = res;
}

// ---------------- proj 1x1 conv + residual (fp32) ----------------
__global__ __launch_bounds__(256) void proj_kernel(
    const float* __restrict__ hh, const float* __restrict__ wp,
    const float* __restrict__ bp, const float* __restrict__ x,
    float* __restrict__ out) {
  __shared__ float hs[C_][32];
  int b = blockIdx.x >> 7;
  int n0 = (blockIdx.x & 127) * 32;
  const float* hp = hh + (size_t)b * C_ * N_ + n0;
  for (int i = threadIdx.x; i < C_ * 32; i += 256)
    hs[i >> 5][i & 31] = hp[(size_t)(i >> 5) * N_ + (i & 31)];
  __syncthreads();
  int n = threadIdx.x & 31;
  int ob = (threadIdx.x >> 5) * 16;
  size_t base = (size_t)b * C_ * N_ + n0 + n;
  for (int oi = 0; oi < 16; ++oi) {
    int o = ob + oi;
    float acc = bp[o];
    const float4* w4 = (const float4*)(wp + (size_t)o * C_);
    #pragma unroll 4
    for (int c4 = 0; c4 < C_ / 4; ++c4) {
      float4 a = w4[c4];
      int c = c4 * 4;
      acc += a.x * hs[c][n] + a.y * hs[c + 1][n] +
             a.z * hs[c + 2][n] + a.w * hs[c + 3][n];
    }
    out[base + (size_t)o * N_] = acc + x[base + (size_t)o * N_];
  }
}

extern "C" void kernel_launch(void* const* d_in, const int* in_sizes, int n_in,
                              void* d_out, int out_size, void* d_ws, size_t ws_size,
                              hipStream_t stream) {
  const float* x        = (const float*)d_in[0];
  const float* gn_scale = (const float*)d_in[1];
  const float* gn_bias  = (const float*)d_in[2];
  const float* wq = (const float*)d_in[3];
  const float* bq = (const float*)d_in[4];
  const float* wk = (const float*)d_in[5];
  const float* bk = (const float*)d_in[6];
  const float* wv = (const float*)d_in[7];
  const float* bv = (const float*)d_in[8];
  const float* wp = (const float*)d_in[9];
  const float* bp = (const float*)d_in[10];
  float* out = (float*)d_out;

  // workspace map (32 MB total):
  // [0,4M):   h bf16 (gn out, qkv in); after qkv dead -> reused: Mv [0,256K), Lv [256K,512K)
  // [4M,8M):  qT bf16   } dead after attn -> reused as h_ fp32 [4M,12M) (merge out, proj in)
  // [8M,12M): kT bf16   }
  // [12M,16M): v bf16
  // [16M,32M): O' bf16 [4 split][B][C][N]
  char* ws = (char*)d_ws;
  ushort* hB = (ushort*)ws;
  float*  Mv = (float*)ws;
  float*  Lv = (float*)(ws + 262144);
  ushort* qT = (ushort*)(ws + (4u << 20));
  ushort* kT = (ushort*)(ws + (8u << 20));
  float*  hO = (float*)(ws + (4u << 20));
  ushort* vB = (ushort*)(ws + (12u << 20));
  ushort* Op = (ushort*)(ws + (16u << 20));

  gn_kernel<<<32, 256, 0, stream>>>(x, gn_scale, gn_bias, hB);
  qkv_kernel<<<512, 256, 0, stream>>>(hB, wq, bq, wk, bk, wv, bv, qT, kT, vB);
  attn_kernel<<<512, 128, 0, stream>>>(qT, kT, vB, Op, Mv, Lv);
  merge_kernel<<<2048, 256, 0, stream>>>(Op, Mv, Lv, hO);
  proj_kernel<<<512, 256, 0, stream>>>(hO, wp, bp, x, out);
}

// Round 4
// 198.720 us; speedup vs baseline: 7.3548x; 2.0626x over previous
//
#include <hip/hip_runtime.h>
#include <math.h>

#define B_ 4
#define C_ 128
#define N_ 4096
#define CG 16
#define NSPLIT 4
#define MT 64
#define KLD 136   // Ks row stride (bf16): 128+8, 16B-aligned
#define VLD 72    // Vs row stride: 64+8, 16B-aligned
#define PLD 72    // Ps row stride: 64+8, 16B-aligned

typedef float floatx4 __attribute__((ext_vector_type(4)));
typedef short short8 __attribute__((ext_vector_type(8)));

__device__ __forceinline__ ushort f2bf(float f) {  // RNE
  unsigned u = __float_as_uint(f);
  return (ushort)((u + 0x7FFF + ((u >> 16) & 1)) >> 16);
}
__device__ __forceinline__ float bf2f(ushort u) {
  return __uint_as_float(((unsigned)u) << 16);
}
// pack two floats -> (hi16(a)<<16)|hi16(b), round-half-up, 3 VALU ops
__device__ __forceinline__ unsigned pkbf(float a, float b) {
  return __builtin_amdgcn_perm(__float_as_uint(a) + 0x8000u,
                               __float_as_uint(b) + 0x8000u, 0x07060302u);
}

// ---------------- zero gstat ----------------
__global__ void zero_kernel(float* g) {
  if (threadIdx.x < 128) g[threadIdx.x] = 0.f;
}

// ---------------- convert 4 weight matrices fp32 -> bf16 ----------------
__global__ __launch_bounds__(256) void wcvt_kernel(
    const float* __restrict__ wq, const float* __restrict__ wk,
    const float* __restrict__ wv, const float* __restrict__ wp,
    ushort* __restrict__ wB) {
  int i = blockIdx.x * 256 + threadIdx.x;   // grid 256 -> 65536
  int m = i >> 14, j = i & 16383;
  const float* src = (m == 0) ? wq : (m == 1) ? wk : (m == 2) ? wv : wp;
  wB[i] = f2bf(src[j]);
}

// ---------------- GN stats: grid 256 = (b, g, part) ----------------
__global__ __launch_bounds__(256) void gn_stats(
    const float* __restrict__ x, float* __restrict__ gstat) {
  int b = blockIdx.x >> 6, g = (blockIdx.x >> 3) & 7, part = blockIdx.x & 7;
  const float4* xp = (const float4*)(x + (size_t)(b * C_ + g * CG) * N_) + part * 2048;
  float s = 0.f, ss = 0.f;
  for (int i = threadIdx.x; i < 2048; i += 256) {
    float4 v = xp[i];
    s += v.x + v.y + v.z + v.w;
    ss += v.x * v.x + v.y * v.y + v.z * v.z + v.w * v.w;
  }
  #pragma unroll
  for (int o = 32; o > 0; o >>= 1) {
    s += __shfl_down(s, o, 64);
    ss += __shfl_down(ss, o, 64);
  }
  __shared__ float rs[4], rss[4];
  int wid = threadIdx.x >> 6, lane = threadIdx.x & 63;
  if (lane == 0) { rs[wid] = s; rss[wid] = ss; }
  __syncthreads();
  if (threadIdx.x == 0) {
    atomicAdd(&gstat[(b * 8 + g) * 2],     rs[0] + rs[1] + rs[2] + rs[3]);
    atomicAdd(&gstat[(b * 8 + g) * 2 + 1], rss[0] + rss[1] + rss[2] + rss[3]);
  }
}

// ---------------- GN apply + transpose -> hT[b][n][c] bf16 ----------------
__global__ __launch_bounds__(256) void gn_apply(
    const float* __restrict__ x, const float* __restrict__ gstat,
    const float* __restrict__ scale, const float* __restrict__ bias,
    ushort* __restrict__ hT) {
  __shared__ __align__(16) ushort tile[64 * KLD];
  __shared__ float sMu[8], sRs[8];
  int b = blockIdx.x >> 6, n0 = (blockIdx.x & 63) * 64;
  int tid = threadIdx.x;
  if (tid < 8) {
    float S = gstat[(b * 8 + tid) * 2], SS = gstat[(b * 8 + tid) * 2 + 1];
    float mu = S * (1.f / 65536.f);
    float var = SS * (1.f / 65536.f) - mu * mu;
    sMu[tid] = mu; sRs[tid] = rsqrtf(var + 1e-6f);
  }
  __syncthreads();
  for (int i = tid; i < 2048; i += 256) {   // 128 c x 16 float4 (64 n)
    int c = i >> 4, n4 = i & 15;
    float4 v = *(const float4*)(x + (size_t)(b * C_ + c) * N_ + n0 + n4 * 4);
    int g = c >> 4;
    float sc = scale[c] * sRs[g], bi = bias[c] - sMu[g] * sc;
    tile[(n4 * 4 + 0) * KLD + c] = f2bf(v.x * sc + bi);
    tile[(n4 * 4 + 1) * KLD + c] = f2bf(v.y * sc + bi);
    tile[(n4 * 4 + 2) * KLD + c] = f2bf(v.z * sc + bi);
    tile[(n4 * 4 + 3) * KLD + c] = f2bf(v.w * sc + bi);
  }
  __syncthreads();
  for (int i = tid; i < 1024; i += 256) {   // 64 n x 16 uint4
    int nl = i >> 4, c8 = i & 15;
    *(uint4*)(hT + (size_t)(b * N_ + n0 + nl) * C_ + c8 * 8) =
        *(const uint4*)&tile[nl * KLD + c8 * 8];
  }
}

// ---------------- QKV via MFMA: grid 512 x 256thr; wave = 16 n x 64 o ----------------
__global__ __launch_bounds__(256) void qkv_kernel(
    const ushort* __restrict__ hT, const ushort* __restrict__ wB,
    const float* __restrict__ bq, const float* __restrict__ bk,
    const float* __restrict__ bv,
    ushort* __restrict__ qT, ushort* __restrict__ kT, ushort* __restrict__ vB) {
  int tid = threadIdx.x, lane = tid & 63, w = tid >> 6;
  int col = lane & 15, quad = lane >> 4;
  int b = blockIdx.x >> 7;
  int n = (blockIdx.x & 127) * 32 + (w & 1) * 16 + col;
  int oh = (w >> 1) * 64;
  const ushort* hrow = hT + ((size_t)b * N_ + n) * C_;
  short8 hf[4];
  #pragma unroll
  for (int kc = 0; kc < 4; ++kc)
    hf[kc] = *(const short8*)(hrow + kc * 32 + quad * 8);
  const ushort* Wq = wB;
  const ushort* Wk = wB + 16384;
  const ushort* Wv = wB + 32768;
  const float scl = 0.12751879752224991f;  // 128^-0.5 * log2(e)
  #pragma unroll
  for (int ot = 0; ot < 4; ++ot) {
    int o0 = oh + ot * 16;
    floatx4 aq = (floatx4)0.f, ak = (floatx4)0.f, av = (floatx4)0.f;
    #pragma unroll
    for (int kc = 0; kc < 4; ++kc) {
      int wo = (o0 + col) * C_ + kc * 32 + quad * 8;
      aq = __builtin_amdgcn_mfma_f32_16x16x32_bf16(*(const short8*)&Wq[wo], hf[kc], aq, 0, 0, 0);
      ak = __builtin_amdgcn_mfma_f32_16x16x32_bf16(*(const short8*)&Wk[wo], hf[kc], ak, 0, 0, 0);
      av = __builtin_amdgcn_mfma_f32_16x16x32_bf16(*(const short8*)&Wv[wo], hf[kc], av, 0, 0, 0);
    }
    float4 bqv = *(const float4*)&bq[o0 + quad * 4];
    float4 bkv = *(const float4*)&bk[o0 + quad * 4];
    float4 bvv = *(const float4*)&bv[o0 + quad * 4];
    float q0 = (aq[0] + bqv.x) * scl, q1 = (aq[1] + bqv.y) * scl;
    float q2 = (aq[2] + bqv.z) * scl, q3 = (aq[3] + bqv.w) * scl;
    uint2 qs = { pkbf(q1, q0), pkbf(q3, q2) };
    uint2 ks = { pkbf(ak[1] + bkv.y, ak[0] + bkv.x), pkbf(ak[3] + bkv.w, ak[2] + bkv.z) };
    *(uint2*)(qT + ((size_t)b * N_ + n) * C_ + o0 + quad * 4) = qs;
    *(uint2*)(kT + ((size_t)b * N_ + n) * C_ + o0 + quad * 4) = ks;
    #pragma unroll
    for (int r = 0; r < 4; ++r) {
      float vv = (r == 0) ? av[0] + bvv.x : (r == 1) ? av[1] + bvv.y
               : (r == 2) ? av[2] + bvv.z : av[3] + bvv.w;
      vB[((size_t)b * C_ + o0 + quad * 4 + r) * N_ + n] = f2bf(vv);
    }
  }
}

// ---------------- MFMA flash attention (S^T form), NSPLIT=4, MT=64 ----------------
// grid 512: sp=bx&3, qblk=(bx>>2)&31, b=bx>>7.  256 thr = 4 waves x 32 q-rows
__global__ __launch_bounds__(256, 2) void attn_kernel(
    const ushort* __restrict__ qT, const ushort* __restrict__ kT,
    const ushort* __restrict__ vB, ushort* __restrict__ Op,
    float* __restrict__ Mv, float* __restrict__ Lv) {
  __shared__ __align__(16) ushort Ks[MT * KLD];   // 17408 B
  __shared__ __align__(16) ushort Vs[C_ * VLD];   // 18432 B
  __shared__ __align__(16) ushort Ps[128 * PLD];  // 18432 B
  __shared__ float alphaS[4][2][16];
  int sp = blockIdx.x & 3;
  int qblk = (blockIdx.x >> 2) & 31;
  int b = blockIdx.x >> 7;
  int n0 = qblk * 128;
  int tid = threadIdx.x, lane = tid & 63, w = tid >> 6;
  int col = lane & 15, quad = lane >> 4;
  const ushort* qTb = qT + ((size_t)b * N_ + n0) * C_;
  const ushort* kTb = kT + (size_t)b * N_ * C_;
  const ushort* vBb = vB + (size_t)b * C_ * N_;

  short8 qf[2][4];   // B-frags, direct from global (L2-resident)
  #pragma unroll
  for (int qt = 0; qt < 2; ++qt)
    #pragma unroll
    for (int kc = 0; kc < 4; ++kc)
      qf[qt][kc] = *(const short8*)(qTb + (size_t)(w * 32 + qt * 16 + col) * C_ + kc * 32 + quad * 8);

  floatx4 Oacc[2][8];
  #pragma unroll
  for (int qt = 0; qt < 2; ++qt)
    #pragma unroll
    for (int ct = 0; ct < 8; ++ct) Oacc[qt][ct] = (floatx4)0.f;
  float mrun[2] = {-1e30f, -1e30f}, lrun[2] = {0.f, 0.f};

  for (int it = 0; it < 1024 / MT; ++it) {
    int m0 = sp * 1024 + it * MT;
    __syncthreads();
    for (int i = tid; i < 1024; i += 256) {          // K: 64 m x 128 c
      int r = i >> 4, c8 = i & 15;
      *(uint4*)&Ks[r * KLD + c8 * 8] = *(const uint4*)(kTb + (size_t)(m0 + r) * C_ + c8 * 8);
    }
    for (int i = tid; i < 1024; i += 256) {          // V: 128 c x 64 m
      int c = i >> 3, m8 = i & 7;
      *(uint4*)&Vs[c * VLD + m8 * 8] = *(const uint4*)(vBb + (size_t)c * N_ + m0 + m8 * 8);
    }
    __syncthreads();

    // S^T tiles: rows m (in-register), cols q
    floatx4 st[2][4];
    #pragma unroll
    for (int mt = 0; mt < 4; ++mt) {
      short8 kf[4];
      #pragma unroll
      for (int kc = 0; kc < 4; ++kc)
        kf[kc] = *(const short8*)&Ks[(mt * 16 + col) * KLD + kc * 32 + quad * 8];
      #pragma unroll
      for (int qt = 0; qt < 2; ++qt) {
        floatx4 acc = (qt == 0 || true) ? (floatx4)0.f : (floatx4)0.f;
        #pragma unroll
        for (int kc = 0; kc < 4; ++kc)
          acc = __builtin_amdgcn_mfma_f32_16x16x32_bf16(kf[kc], qf[qt][kc], acc, 0, 0, 0);
        st[qt][mt] = acc;
      }
    }
    // online softmax: lane owns q = w*32+qt*16+col; m = mt*16+quad*4+r (16 vals in-reg)
    #pragma unroll
    for (int qt = 0; qt < 2; ++qt) {
      float mx = st[qt][0][0];
      #pragma unroll
      for (int mt = 0; mt < 4; ++mt)
        #pragma unroll
        for (int r = 0; r < 4; ++r) mx = fmaxf(mx, st[qt][mt][r]);
      mx = fmaxf(mx, __shfl_xor(mx, 16, 64));
      mx = fmaxf(mx, __shfl_xor(mx, 32, 64));
      float mnew = fmaxf(mrun[qt], mx);
      float al = exp2f(mrun[qt] - mnew);
      mrun[qt] = mnew;
      float lsum = 0.f;
      int prow = (w * 32 + qt * 16 + col) * PLD;
      #pragma unroll
      for (int mt = 0; mt < 4; ++mt) {
        float p0 = exp2f(st[qt][mt][0] - mnew);
        float p1 = exp2f(st[qt][mt][1] - mnew);
        float p2 = exp2f(st[qt][mt][2] - mnew);
        float p3 = exp2f(st[qt][mt][3] - mnew);
        lsum += (p0 + p1) + (p2 + p3);
        uint2 pk = { pkbf(p1, p0), pkbf(p3, p2) };
        *(uint2*)&Ps[prow + mt * 16 + quad * 4] = pk;
      }
      lsum += __shfl_xor(lsum, 16, 64);
      lsum += __shfl_xor(lsum, 32, 64);
      lrun[qt] = lrun[qt] * al + lsum;
      if (quad == 0) alphaS[w][qt][col] = al;
    }
    // rescale O (rows q = quad*4+r)
    #pragma unroll
    for (int qt = 0; qt < 2; ++qt) {
      float a0 = alphaS[w][qt][quad * 4 + 0];
      float a1 = alphaS[w][qt][quad * 4 + 1];
      float a2 = alphaS[w][qt][quad * 4 + 2];
      float a3 = alphaS[w][qt][quad * 4 + 3];
      #pragma unroll
      for (int ct = 0; ct < 8; ++ct) {
        Oacc[qt][ct][0] *= a0; Oacc[qt][ct][1] *= a1;
        Oacc[qt][ct][2] *= a2; Oacc[qt][ct][3] *= a3;
      }
    }
    // PV: A = P[q][m], B = V[c][m]
    short8 pf[2][2];
    #pragma unroll
    for (int qt = 0; qt < 2; ++qt)
      #pragma unroll
      for (int kh = 0; kh < 2; ++kh)
        pf[qt][kh] = *(const short8*)&Ps[(w * 32 + qt * 16 + col) * PLD + kh * 32 + quad * 8];
    #pragma unroll
    for (int ct = 0; ct < 8; ++ct) {
      short8 vf0 = *(const short8*)&Vs[(ct * 16 + col) * VLD + quad * 8];
      short8 vf1 = *(const short8*)&Vs[(ct * 16 + col) * VLD + 32 + quad * 8];
      #pragma unroll
      for (int qt = 0; qt < 2; ++qt) {
        Oacc[qt][ct] = __builtin_amdgcn_mfma_f32_16x16x32_bf16(pf[qt][0], vf0, Oacc[qt][ct], 0, 0, 0);
        Oacc[qt][ct] = __builtin_amdgcn_mfma_f32_16x16x32_bf16(pf[qt][1], vf1, Oacc[qt][ct], 0, 0, 0);
      }
    }
  }
  // epilogue: Op[sp][b][n][c] bf16 (unnormalized) + m,l
  ushort* OpB = Op + (((size_t)sp * B_ + b) * N_ + n0) * C_;
  #pragma unroll
  for (int qt = 0; qt < 2; ++qt)
    #pragma unroll
    for (int ct = 0; ct < 8; ++ct)
      #pragma unroll
      for (int r = 0; r < 4; ++r) {
        int n = w * 32 + qt * 16 + quad * 4 + r;
        OpB[(size_t)n * C_ + ct * 16 + col] = f2bf(Oacc[qt][ct][r]);
      }
  if (quad == 0) {
    #pragma unroll
    for (int qt = 0; qt < 2; ++qt) {
      int n = b * N_ + n0 + w * 32 + qt * 16 + col;
      Mv[(size_t)sp * (B_ * N_) + n] = mrun[qt];
      Lv[(size_t)sp * (B_ * N_) + n] = lrun[qt];
    }
  }
}

// ---------------- merge 4 splits; normalize; write h_T in-place over Op[0] ----------------
__global__ __launch_bounds__(256) void merge_kernel(
    ushort* __restrict__ Op, const float* __restrict__ Mv,
    const float* __restrict__ Lv) {
  int t = blockIdx.x * 256 + threadIdx.x;   // grid 1024 -> 262144
  int c8 = (t & 15) * 8;
  int nIdx = t >> 4;                        // b*N + n
  float m[NSPLIT], l[NSPLIT];
  #pragma unroll
  for (int sp = 0; sp < NSPLIT; ++sp) {
    m[sp] = Mv[sp * (B_ * N_) + nIdx];
    l[sp] = Lv[sp * (B_ * N_) + nIdx];
  }
  float M = fmaxf(fmaxf(m[0], m[1]), fmaxf(m[2], m[3]));
  float wg[NSPLIT], den = 0.f;
  #pragma unroll
  for (int sp = 0; sp < NSPLIT; ++sp) { wg[sp] = exp2f(m[sp] - M); den += wg[sp] * l[sp]; }
  float inv = 1.f / den;
  float o[8];
  #pragma unroll
  for (int j = 0; j < 8; ++j) o[j] = 0.f;
  #pragma unroll
  for (int sp = 0; sp < NSPLIT; ++sp) {
    uint4 d = *(const uint4*)&Op[((size_t)sp * (B_ * N_) + nIdx) * C_ + c8];
    unsigned dd[4] = {d.x, d.y, d.z, d.w};
    #pragma unroll
    for (int j = 0; j < 4; ++j) {
      o[j * 2]     += wg[sp] * bf2f((ushort)(dd[j] & 0xFFFF));
      o[j * 2 + 1] += wg[sp] * bf2f((ushort)(dd[j] >> 16));
    }
  }
  uint4 res;
  res.x = pkbf(o[1] * inv, o[0] * inv);
  res.y = pkbf(o[3] * inv, o[2] * inv);
  res.z = pkbf(o[5] * inv, o[4] * inv);
  res.w = pkbf(o[7] * inv, o[6] * inv);
  *(uint4*)&Op[(size_t)nIdx * C_ + c8] = res;   // sp=0 slice, same (n,c) -> no hazard
}

// ---------------- proj via MFMA + residual (fp32 out) ----------------
__global__ __launch_bounds__(256) void proj_kernel(
    const ushort* __restrict__ hT2, const ushort* __restrict__ wpB,
    const float* __restrict__ bp, const float* __restrict__ x,
    float* __restrict__ out) {
  int tid = threadIdx.x, lane = tid & 63, w = tid >> 6;
  int col = lane & 15, quad = lane >> 4;
  int b = blockIdx.x >> 7;
  int n = (blockIdx.x & 127) * 32 + (w & 1) * 16 + col;
  int oh = (w >> 1) * 64;
  const ushort* hrow = hT2 + ((size_t)b * N_ + n) * C_;
  short8 hf[4];
  #pragma unroll
  for (int kc = 0; kc < 4; ++kc)
    hf[kc] = *(const short8*)(hrow + kc * 32 + quad * 8);
  #pragma unroll
  for (int ot = 0; ot < 4; ++ot) {
    int o0 = oh + ot * 16;
    floatx4 acc = (floatx4)0.f;
    #pragma unroll
    for (int kc = 0; kc < 4; ++kc) {
      int wo = (o0 + col) * C_ + kc * 32 + quad * 8;
      acc = __builtin_amdgcn_mfma_f32_16x16x32_bf16(*(const short8*)&wpB[wo], hf[kc], acc, 0, 0, 0);
    }
    float4 bpv = *(const float4*)&bp[o0 + quad * 4];
    float bb[4] = {bpv.x, bpv.y, bpv.z, bpv.w};
    #pragma unroll
    for (int r = 0; r < 4; ++r) {
      size_t idx = ((size_t)b * C_ + o0 + quad * 4 + r) * N_ + n;
      out[idx] = acc[r] + bb[r] + x[idx];
    }
  }
}

extern "C" void kernel_launch(void* const* d_in, const int* in_sizes, int n_in,
                              void* d_out, int out_size, void* d_ws, size_t ws_size,
                              hipStream_t stream) {
  const float* x        = (const float*)d_in[0];
  const float* gn_scale = (const float*)d_in[1];
  const float* gn_bias  = (const float*)d_in[2];
  const float* wq = (const float*)d_in[3];
  const float* bq = (const float*)d_in[4];
  const float* wk = (const float*)d_in[5];
  const float* bk = (const float*)d_in[6];
  const float* wv = (const float*)d_in[7];
  const float* bv = (const float*)d_in[8];
  const float* wp = (const float*)d_in[9];
  const float* bp = (const float*)d_in[10];
  float* out = (float*)d_out;

  // workspace map (32 MB):
  // [0,256K) Mv | [256K,512K) Lv | [512K,640K) wB (4x32KB bf16) | [640K,+512B) gstat
  // [4M,8M) qT | [8M,12M) kT | [12M,16M) vB
  // [16M,32M) Op[4][B][N][C] bf16;  hT(gn out/qkv in) overlays Op[0] pre-attn;
  //           h_T(merge out/proj in) = Op[0] post-merge (in-place)
  char* ws = (char*)d_ws;
  float*  Mv    = (float*)ws;
  float*  Lv    = (float*)(ws + 262144);
  ushort* wB    = (ushort*)(ws + 524288);
  float*  gstat = (float*)(ws + 655360);
  ushort* qT    = (ushort*)(ws + (4u << 20));
  ushort* kT    = (ushort*)(ws + (8u << 20));
  ushort* vB    = (ushort*)(ws + (12u << 20));
  ushort* Op    = (ushort*)(ws + (16u << 20));
  ushort* hT    = Op;        // dead before attn writes Op
  ushort* wpB   = wB + 49152;

  zero_kernel<<<1, 128, 0, stream>>>(gstat);
  wcvt_kernel<<<256, 256, 0, stream>>>(wq, wk, wv, wp, wB);
  gn_stats<<<256, 256, 0, stream>>>(x, gstat);
  gn_apply<<<256, 256, 0, stream>>>(x, gstat, gn_scale, gn_bias, hT);
  qkv_kernel<<<512, 256, 0, stream>>>(hT, wB, bq, bk, bv, qT, kT, vB);
  attn_kernel<<<512, 256, 0, stream>>>(qT, kT, vB, Op, Mv, Lv);
  merge_kernel<<<1024, 256, 0, stream>>>(Op, Mv, Lv);
  proj_kernel<<<512, 256, 0, stream>>>(Op, wpB, bp, x, out);
}